// Round 8
// baseline (1774.259 us; speedup 1.0000x reference)
//
#include <hip/hip_runtime.h>

// GCN 2-layer on MI355X. R8: slice-major feature layout + XCD-affine
// (bucket,slice) aggregation with LDS f32 accumulation.
//   h stored as [slice][node][16 f16] (slice = 16 features, 3.2MB for D=128).
//   agg block = (bucket b, slice s), s = blockIdx % NSLICE -> XCD s only
//   touches slice s (fits 4MB L2; R6/R7 FETCH was 8 XCD x full 25.6MB h).
//   Edge-parallel: thread reads packed (src<<8|local_dst) payload, gathers
//   32B of h-slice, ds_add_f32 into bank-padded LDS acc[256][17].
// Deleted: padded CSR, bucket_fill, degree sort (edge-parallel is balanced).
// GEMMs read/write slice-major (8-f16 fragments never cross a slice).

#define NN 100000
#define EE 1600000
#define NB 391              // buckets of 256 nodes
#define BCAP 4608           // col32 slots per bucket (mean 4092, +8 sigma)
#define EPB 8192            // edges per partition block
#define PBLK ((EE + EPB - 1) / EPB)  // 196

typedef _Float16 f16;
typedef _Float16 f16x8 __attribute__((ext_vector_type(8)));
typedef float f32x4 __attribute__((ext_vector_type(4)));

__device__ __forceinline__ int load_idx(const void* p, long long i, int is64) {
    if (is64) return (int)((const long long*)p)[i];
    return ((const int*)p)[i];
}

// ---------- bucket cursor init ----------
__global__ void init_buckets(int* cursor) {
    int i = blockIdx.x * 256 + threadIdx.x;
    if (i < NB) cursor[i] = i * BCAP;
}

// ---------- partition: edges -> bucket-major packed payloads (fixed-cap) ----------
__global__ __launch_bounds__(256) void partition_kernel(const void* ei,
                                                        int* __restrict__ cursor,
                                                        unsigned* __restrict__ col32) {
    __shared__ int lh[NB], lbase[NB], lfill[NB];
    __shared__ int s_is64;
    for (int i = threadIdx.x; i < NB; i += 256) { lh[i] = 0; lfill[i] = 0; }
    if (threadIdx.x == 0) {
        const unsigned* w = (const unsigned*)ei;
        unsigned acc = 0;
        #pragma unroll
        for (int k = 0; k < 8; k++) acc |= w[2 * (k * 997 + 1) + 1];
        s_is64 = (acc == 0);
    }
    __syncthreads();
    int is64 = s_is64;
    long long base = (long long)blockIdx.x * EPB;
    #pragma unroll 4
    for (int k = 0; k < EPB / 256; k++) {
        long long i = base + k * 256 + threadIdx.x;
        if (i < EE) {
            int d = load_idx(ei, (long long)EE + i, is64);
            atomicAdd(&lh[d >> 8], 1);
        }
    }
    __syncthreads();
    for (int i = threadIdx.x; i < NB; i += 256)
        lbase[i] = lh[i] ? atomicAdd(&cursor[i], lh[i]) : 0;
    __syncthreads();
    #pragma unroll 4
    for (int k = 0; k < EPB / 256; k++) {
        long long i = base + k * 256 + threadIdx.x;
        if (i < EE) {
            int s = load_idx(ei, i, is64);
            int d = load_idx(ei, (long long)EE + i, is64);
            int b = d >> 8;
            int r = atomicAdd(&lfill[b], 1);
            col32[lbase[b] + r] = ((unsigned)s << 8) | (unsigned)(d & 255);
        }
    }
}

// ---------- per-bucket degree count -> dinv ----------
__global__ __launch_bounds__(256) void count_dinv(const unsigned* __restrict__ col32,
                                                  const int* __restrict__ cursor,
                                                  float* __restrict__ dinv) {
    __shared__ int cnt[256];
    int t = threadIdx.x, b = blockIdx.x;
    cnt[t] = 0;
    __syncthreads();
    int base = b * BCAP, end = cursor[b];
    for (int i = base + t; i < end; i += 256)
        atomicAdd(&cnt[col32[i] & 255u], 1);
    __syncthreads();
    int node = b * 256 + t;
    if (node < NN) dinv[node] = rsqrtf((float)(cnt[t] + 1));  // +1 = self loop
}

// ---------- weight prep: split fp32 W into f16 hi/lo, transposed, XOR-swizzled ----------
__global__ void prep_split(const float* __restrict__ W1, const float* __restrict__ W2,
                           f16* __restrict__ W1h, f16* __restrict__ W1l,
                           f16* __restrict__ W2h, f16* __restrict__ W2l) {
    int t = blockIdx.x * 256 + threadIdx.x;
    if (t < 128 * 128) {
        int k = t >> 7, n = t & 127;
        float v = W1[t];
        f16 h = (f16)v;
        f16 l = (f16)(v - (float)h);
        int idx = n * 128 + (k ^ ((n & 7) << 3));
        W1h[idx] = h; W1l[idx] = l;
    } else if (t < 128 * 128 + 128 * 64) {
        int u = t - 128 * 128;
        int k = u >> 6, n = u & 63;
        float v = W2[u];
        f16 h = (f16)v;
        f16 l = (f16)(v - (float)h);
        int idx = n * 128 + (k ^ ((n & 7) << 3));
        W2h[idx] = h; W2l[idx] = l;
    }
}

// ---------- GEMM via f16 MFMA, hi/lo split; slice-major H out, prescaled ----------
// SPLIT_A=1: X fp32 row-major. SPLIT_A=0: X f16 slice-major [s][node][16].
template <int M, int SPLIT_A>
__global__ __launch_bounds__(256) void gemm_mfma(const void* __restrict__ Xv,
                                                 const f16* __restrict__ Wh,
                                                 const f16* __restrict__ Wl,
                                                 const float* __restrict__ dinv,
                                                 f16* __restrict__ H) {
    __shared__ f16 wsh[M * 128];
    __shared__ f16 wsl[M * 128];
    const int tid = threadIdx.x;
    for (int c = tid; c < M * 16; c += 256) {
        *(float4*)&wsh[c * 8] = ((const float4*)Wh)[c];
        *(float4*)&wsl[c * 8] = ((const float4*)Wl)[c];
    }
    __syncthreads();

    const int lane = tid & 63;
    const int wv = tid >> 6;
    const int m0 = lane & 15;
    const int kg = lane >> 4;
    int row = blockIdx.x * 64 + wv * 16 + m0;
    if (row >= NN) row = NN - 1;  // clamp; stores are guarded

    constexpr int NT = M / 16;
    f32x4 acc[NT];
    #pragma unroll
    for (int i = 0; i < NT; i++) acc[i] = (f32x4){0.f, 0.f, 0.f, 0.f};

    #pragma unroll
    for (int kt = 0; kt < 4; ++kt) {
        int k0 = kt * 32 + kg * 8;
        f16x8 ah, al;
        if (SPLIT_A) {
            const float* xr = (const float*)Xv + (size_t)row * 128 + k0;
            float xv[8];
            *(float4*)&xv[0] = *(const float4*)xr;
            *(float4*)&xv[4] = *(const float4*)(xr + 4);
            #pragma unroll
            for (int r = 0; r < 8; r++) {
                ah[r] = (f16)xv[r];
                al[r] = (f16)(xv[r] - (float)ah[r]);
            }
        } else {
            const f16* xp = (const f16*)Xv;
            ah = *(const f16x8*)(xp + ((size_t)(k0 >> 4) * NN + row) * 16 + (k0 & 15));
        }
        #pragma unroll
        for (int nt = 0; nt < NT; ++nt) {
            int n = nt * 16 + m0;
            int sch = (kt * 4 + kg) ^ (n & 7);
            int off = n * 128 + sch * 8;
            f16x8 bh = *(const f16x8*)&wsh[off];
            f16x8 bl = *(const f16x8*)&wsl[off];
            acc[nt] = __builtin_amdgcn_mfma_f32_16x16x32_f16(ah, bh, acc[nt], 0, 0, 0);
            if (SPLIT_A)
                acc[nt] = __builtin_amdgcn_mfma_f32_16x16x32_f16(al, bh, acc[nt], 0, 0, 0);
            acc[nt] = __builtin_amdgcn_mfma_f32_16x16x32_f16(ah, bl, acc[nt], 0, 0, 0);
        }
    }

    // C/D layout (m89-verified): col = lane&15, row = (lane>>4)*4 + reg
    // H slice-major: element (r, cidx=nt*16+m0) -> H[(nt*NN + r)*16 + m0]
    int r0 = blockIdx.x * 64 + wv * 16 + kg * 4;
    float dv[4];
    #pragma unroll
    for (int i = 0; i < 4; i++) {
        int r = r0 + i;
        dv[i] = (r < NN) ? dinv[r] : 0.f;
    }
    #pragma unroll
    for (int nt = 0; nt < NT; ++nt) {
        #pragma unroll
        for (int i = 0; i < 4; i++) {
            int r = r0 + i;
            if (r < NN) H[((size_t)nt * NN + r) * 16 + m0] = (f16)(acc[nt][i] * dv[i]);
        }
    }
}

// ---------- aggregation: block = (bucket, slice); LDS f32 accumulation ----------
// hs: prescaled slice-major [NSLICE][NN][16]. out: OUT16 ? slice-major f16
// (layer-1, relu) : row-major f32 (final, no relu).
template <int NSLICE, bool RELU, bool OUT16>
__global__ __launch_bounds__(256) void agg_lds(const f16* __restrict__ hs,
                                               const unsigned* __restrict__ col32,
                                               const int* __restrict__ cursor,
                                               const float* __restrict__ dinv,
                                               const float* __restrict__ bias,
                                               void* __restrict__ outv) {
    __shared__ float acc[256][17];  // +1 pad: spreads per-f banks across nodes
    int t = threadIdx.x;
    int b = blockIdx.x / NSLICE;
    int s = blockIdx.x % NSLICE;  // slice fastest -> XCD affinity via %8 dispatch
    #pragma unroll
    for (int i = 0; i < 17; i++) acc[t][i] = 0.f;
    __syncthreads();
    int base = b * BCAP, end = cursor[b];
    const f16x8* hp = (const f16x8*)(hs + (size_t)s * NN * 16);
    for (int i = base + t; i < end; i += 256) {
        unsigned p = col32[i];
        int src = (int)(p >> 8);
        int ld = (int)(p & 255u);
        f16x8 v0 = hp[(unsigned)(src * 2)];
        f16x8 v1 = hp[(unsigned)(src * 2 + 1)];
        #pragma unroll
        for (int k = 0; k < 8; k++) atomicAdd(&acc[ld][k], (float)v0[k]);
        #pragma unroll
        for (int k = 0; k < 8; k++) atomicAdd(&acc[ld][k + 8], (float)v1[k]);
    }
    __syncthreads();
    int node = b * 256 + t;
    if (node >= NN) return;
    float di = dinv[node];
    f16x8 s0 = hp[(unsigned)(node * 2)];
    f16x8 s1 = hp[(unsigned)(node * 2 + 1)];
    const float* bp = bias + s * 16;
    float o[16];
    #pragma unroll
    for (int k = 0; k < 8; k++) o[k] = fmaf(acc[t][k] + (float)s0[k], di, bp[k]);
    #pragma unroll
    for (int k = 0; k < 8; k++) o[k + 8] = fmaf(acc[t][k + 8] + (float)s1[k], di, bp[k + 8]);
    if (RELU) {
        #pragma unroll
        for (int k = 0; k < 16; k++) o[k] = fmaxf(o[k], 0.f);
    }
    if (OUT16) {
        f16x8 w0, w1;
        #pragma unroll
        for (int k = 0; k < 8; k++) { w0[k] = (f16)o[k]; w1[k] = (f16)o[k + 8]; }
        f16x8* op = (f16x8*)outv;
        op[((size_t)s * NN + node) * 2] = w0;
        op[((size_t)s * NN + node) * 2 + 1] = w1;
    } else {
        float* op = (float*)outv + (size_t)node * (NSLICE * 16) + s * 16;
        #pragma unroll
        for (int k = 0; k < 4; k++)
            *(float4*)(op + k * 4) = make_float4(o[k * 4], o[k * 4 + 1], o[k * 4 + 2], o[k * 4 + 3]);
    }
}

extern "C" void kernel_launch(void* const* d_in, const int* in_sizes, int n_in,
                              void* d_out, int out_size, void* d_ws, size_t ws_size,
                              hipStream_t stream) {
    const float* x  = (const float*)d_in[0];
    const void*  ei = d_in[1];
    const float* W1 = (const float*)d_in[2];
    const float* b1 = (const float*)d_in[3];
    const float* W2 = (const float*)d_in[4];
    const float* b2 = (const float*)d_in[5];
    float* out = (float*)d_out;

    char* wsp = (char*)d_ws;
    size_t off = 0;
    auto alloc = [&](size_t bytes) {
        void* p = wsp + off;
        off += (bytes + 255) & ~(size_t)255;
        return p;
    };
    f16*      h1     = (f16*)alloc((size_t)NN * 128 * 2);  // slice-major [8][NN][16]
    f16*      a1     = (f16*)alloc((size_t)NN * 128 * 2);  // slice-major [8][NN][16]
    f16*      h2     = (f16*)alloc((size_t)NN * 64 * 2);   // slice-major [4][NN][16]
    unsigned* col32  = (unsigned*)alloc((size_t)NB * BCAP * 4);  // 7.2MB
    float*    dinv   = (float*)alloc((size_t)NN * 4);
    int*      cursor = (int*)alloc((size_t)NB * 4);
    f16*      W1h    = (f16*)alloc(128 * 128 * 2);
    f16*      W1l    = (f16*)alloc(128 * 128 * 2);
    f16*      W2h    = (f16*)alloc(64 * 128 * 2);
    f16*      W2l    = (f16*)alloc(64 * 128 * 2);
    (void)ws_size; (void)in_sizes; (void)n_in; (void)out_size;

    prep_split<<<96, 256, 0, stream>>>(W1, W2, W1h, W1l, W2h, W2l);
    init_buckets<<<2, 256, 0, stream>>>(cursor);
    partition_kernel<<<PBLK, 256, 0, stream>>>(ei, cursor, col32);
    count_dinv<<<NB, 256, 0, stream>>>(col32, cursor, dinv);

    gemm_mfma<128, 1><<<(NN + 63) / 64, 256, 0, stream>>>(x, W1h, W1l, dinv, h1);
    agg_lds<8, true, true><<<NB * 8, 256, 0, stream>>>(h1, col32, cursor, dinv, b1, a1);
    gemm_mfma<64, 0><<<(NN + 63) / 64, 256, 0, stream>>>(a1, W2h, W2l, dinv, h2);
    agg_lds<4, false, false><<<NB * 4, 256, 0, stream>>>(h2, col32, cursor, dinv, b2, out);
}

// Round 9
// 274.051 us; speedup vs baseline: 6.4742x; 6.4742x over previous
//
#include <hip/hip_runtime.h>

// GCN 2-layer on MI355X. R9 = R8's slice-major XCD-affine layout (verified:
// FETCH 194->42MB) with the LDS-atomic accumulator replaced by per-THREAD
// register accumulation: thread = (node, 16-feature slice), 16 f32 acc in
// VGPRs, serial edge loop unrolled x4 (8 gathers in flight), no LDS/atomics.
//   h slice-major [NSLICE][NN][16 f16], prescaled by dinv in GEMM epilogue.
//   agg block = (bucket of 256 nodes, slice s), s = blockIdx % NSLICE -> each
//   XCD touches one 3.2MB slice (fits 4MB L2).

#define NN 100000
#define EE 1600000
#define NB 391              // buckets of 256 nodes
#define BCAP 4608           // col slots per bucket (mean 4092, +8 sigma)
#define EPB 8192            // edges per partition block
#define PBLK ((EE + EPB - 1) / EPB)  // 196

typedef _Float16 f16;
typedef _Float16 f16x8 __attribute__((ext_vector_type(8)));
typedef float f32x4 __attribute__((ext_vector_type(4)));

__device__ __forceinline__ int load_idx(const void* p, long long i, int is64) {
    if (is64) return (int)((const long long*)p)[i];
    return ((const int*)p)[i];
}

// ---------- bucket cursor init ----------
__global__ void init_buckets(int* cursor) {
    int i = blockIdx.x * 256 + threadIdx.x;
    if (i < NB) cursor[i] = i * BCAP;
}

// ---------- partition: edges -> bucket-major packed payloads (fixed-cap) ----------
__global__ __launch_bounds__(256) void partition_kernel(const void* ei,
                                                        int* __restrict__ cursor,
                                                        unsigned* __restrict__ col32) {
    __shared__ int lh[NB], lbase[NB], lfill[NB];
    __shared__ int s_is64;
    for (int i = threadIdx.x; i < NB; i += 256) { lh[i] = 0; lfill[i] = 0; }
    if (threadIdx.x == 0) {
        const unsigned* w = (const unsigned*)ei;
        unsigned acc = 0;
        #pragma unroll
        for (int k = 0; k < 8; k++) acc |= w[2 * (k * 997 + 1) + 1];
        s_is64 = (acc == 0);
    }
    __syncthreads();
    int is64 = s_is64;
    long long base = (long long)blockIdx.x * EPB;
    #pragma unroll 4
    for (int k = 0; k < EPB / 256; k++) {
        long long i = base + k * 256 + threadIdx.x;
        if (i < EE) {
            int d = load_idx(ei, (long long)EE + i, is64);
            atomicAdd(&lh[d >> 8], 1);
        }
    }
    __syncthreads();
    for (int i = threadIdx.x; i < NB; i += 256)
        lbase[i] = lh[i] ? atomicAdd(&cursor[i], lh[i]) : 0;
    __syncthreads();
    #pragma unroll 4
    for (int k = 0; k < EPB / 256; k++) {
        long long i = base + k * 256 + threadIdx.x;
        if (i < EE) {
            int s = load_idx(ei, i, is64);
            int d = load_idx(ei, (long long)EE + i, is64);
            int b = d >> 8;
            int r = atomicAdd(&lfill[b], 1);
            col32[lbase[b] + r] = ((unsigned)s << 8) | (unsigned)(d & 255);
        }
    }
}

// ---------- per-bucket fill: counts/scan in LDS -> rsp/dinv/col (no padding) ----------
__global__ __launch_bounds__(256) void bucket_fill_kernel(const unsigned* __restrict__ col32,
                                                          const int* __restrict__ cursor,
                                                          int2* __restrict__ rsp,
                                                          float* __restrict__ dinv,
                                                          int* __restrict__ col) {
    __shared__ int cnt[256], incl[256], lfill[256];
    int t = threadIdx.x, b = blockIdx.x;
    cnt[t] = 0; lfill[t] = 0;
    __syncthreads();
    int base = b * BCAP, end = cursor[b];
    for (int i = base + t; i < end; i += 256)
        atomicAdd(&cnt[col32[i] & 255u], 1);
    __syncthreads();
    incl[t] = cnt[t];
    __syncthreads();
    #pragma unroll
    for (int off = 1; off < 256; off <<= 1) {
        int v = (t >= off) ? incl[t - off] : 0;
        __syncthreads();
        if (t >= off) incl[t] += v;
        __syncthreads();
    }
    int node = b * 256 + t;
    if (node < NN) {
        rsp[node] = make_int2(base + incl[t] - cnt[t], cnt[t]);
        dinv[node] = rsqrtf((float)(cnt[t] + 1));  // +1 = self loop
    }
    __syncthreads();
    for (int i = base + t; i < end; i += 256) {
        unsigned p = col32[i];
        int d = p & 255u;
        int r = atomicAdd(&lfill[d], 1);
        col[base + incl[d] - cnt[d] + r] = (int)(p >> 8);
    }
}

// ---------- weight prep: split fp32 W into f16 hi/lo, transposed, XOR-swizzled ----------
__global__ void prep_split(const float* __restrict__ W1, const float* __restrict__ W2,
                           f16* __restrict__ W1h, f16* __restrict__ W1l,
                           f16* __restrict__ W2h, f16* __restrict__ W2l) {
    int t = blockIdx.x * 256 + threadIdx.x;
    if (t < 128 * 128) {
        int k = t >> 7, n = t & 127;
        float v = W1[t];
        f16 h = (f16)v;
        f16 l = (f16)(v - (float)h);
        int idx = n * 128 + (k ^ ((n & 7) << 3));
        W1h[idx] = h; W1l[idx] = l;
    } else if (t < 128 * 128 + 128 * 64) {
        int u = t - 128 * 128;
        int k = u >> 6, n = u & 63;
        float v = W2[u];
        f16 h = (f16)v;
        f16 l = (f16)(v - (float)h);
        int idx = n * 128 + (k ^ ((n & 7) << 3));
        W2h[idx] = h; W2l[idx] = l;
    }
}

// ---------- GEMM via f16 MFMA, hi/lo split; slice-major H out, prescaled ----------
// SPLIT_A=1: X fp32 row-major. SPLIT_A=0: X f16 slice-major [s][node][16].
template <int M, int SPLIT_A>
__global__ __launch_bounds__(256) void gemm_mfma(const void* __restrict__ Xv,
                                                 const f16* __restrict__ Wh,
                                                 const f16* __restrict__ Wl,
                                                 const float* __restrict__ dinv,
                                                 f16* __restrict__ H) {
    __shared__ f16 wsh[M * 128];
    __shared__ f16 wsl[M * 128];
    const int tid = threadIdx.x;
    for (int c = tid; c < M * 16; c += 256) {
        *(float4*)&wsh[c * 8] = ((const float4*)Wh)[c];
        *(float4*)&wsl[c * 8] = ((const float4*)Wl)[c];
    }
    __syncthreads();

    const int lane = tid & 63;
    const int wv = tid >> 6;
    const int m0 = lane & 15;
    const int kg = lane >> 4;
    int row = blockIdx.x * 64 + wv * 16 + m0;
    if (row >= NN) row = NN - 1;  // clamp; stores are guarded

    constexpr int NT = M / 16;
    f32x4 acc[NT];
    #pragma unroll
    for (int i = 0; i < NT; i++) acc[i] = (f32x4){0.f, 0.f, 0.f, 0.f};

    #pragma unroll
    for (int kt = 0; kt < 4; ++kt) {
        int k0 = kt * 32 + kg * 8;
        f16x8 ah, al;
        if (SPLIT_A) {
            const float* xr = (const float*)Xv + (size_t)row * 128 + k0;
            float xv[8];
            *(float4*)&xv[0] = *(const float4*)xr;
            *(float4*)&xv[4] = *(const float4*)(xr + 4);
            #pragma unroll
            for (int r = 0; r < 8; r++) {
                ah[r] = (f16)xv[r];
                al[r] = (f16)(xv[r] - (float)ah[r]);
            }
        } else {
            const f16* xp = (const f16*)Xv;
            ah = *(const f16x8*)(xp + ((size_t)(k0 >> 4) * NN + row) * 16 + (k0 & 15));
        }
        #pragma unroll
        for (int nt = 0; nt < NT; ++nt) {
            int n = nt * 16 + m0;
            int sch = (kt * 4 + kg) ^ (n & 7);
            int off = n * 128 + sch * 8;
            f16x8 bh = *(const f16x8*)&wsh[off];
            f16x8 bl = *(const f16x8*)&wsl[off];
            acc[nt] = __builtin_amdgcn_mfma_f32_16x16x32_f16(ah, bh, acc[nt], 0, 0, 0);
            if (SPLIT_A)
                acc[nt] = __builtin_amdgcn_mfma_f32_16x16x32_f16(al, bh, acc[nt], 0, 0, 0);
            acc[nt] = __builtin_amdgcn_mfma_f32_16x16x32_f16(ah, bl, acc[nt], 0, 0, 0);
        }
    }

    // C/D layout (m89-verified): col = lane&15, row = (lane>>4)*4 + reg
    // H slice-major: element (r, cidx=nt*16+m0) -> H[(nt*NN + r)*16 + m0]
    int r0 = blockIdx.x * 64 + wv * 16 + kg * 4;
    float dv[4];
    #pragma unroll
    for (int i = 0; i < 4; i++) {
        int r = r0 + i;
        dv[i] = (r < NN) ? dinv[r] : 0.f;
    }
    #pragma unroll
    for (int nt = 0; nt < NT; ++nt) {
        #pragma unroll
        for (int i = 0; i < 4; i++) {
            int r = r0 + i;
            if (r < NN) H[((size_t)nt * NN + r) * 16 + m0] = (f16)(acc[nt][i] * dv[i]);
        }
    }
}

// ---------- aggregation: thread = (node, slice); register accumulation ----------
// hs prescaled slice-major [NSLICE][NN][16]. OUT16: slice-major f16 out
// (layer 1, relu); else row-major f32 out (final layer).
template <int NSLICE, bool RELU, bool OUT16>
__global__ __launch_bounds__(256) void agg_seq(const f16* __restrict__ hs,
                                               const int2* __restrict__ rsp,
                                               const int* __restrict__ col,
                                               const float* __restrict__ dinv,
                                               const float* __restrict__ bias,
                                               void* __restrict__ outv) {
    int t = threadIdx.x;
    int b = blockIdx.x / NSLICE;
    int s = blockIdx.x % NSLICE;  // slice fastest -> XCD s sees only slice s%NSLICE
    int node = b * 256 + t;
    if (node >= NN) return;
    const f16x8* hp = (const f16x8*)(hs + (size_t)s * NN * 16);
    int2 g = rsp[node];
    int j = g.x, e = g.x + g.y;
    float a0[16], a1[16];
    #pragma unroll
    for (int k = 0; k < 16; k++) { a0[k] = 0.f; a1[k] = 0.f; }
    // 4 edges/iter: 8 x 16B gathers in flight, 2 independent accumulator sets
    for (; j + 4 <= e; j += 4) {
        int c0 = col[j], c1 = col[j + 1], c2 = col[j + 2], c3 = col[j + 3];
        f16x8 v0 = hp[(unsigned)(c0 * 2)], v1 = hp[(unsigned)(c0 * 2 + 1)];
        f16x8 v2 = hp[(unsigned)(c1 * 2)], v3 = hp[(unsigned)(c1 * 2 + 1)];
        f16x8 v4 = hp[(unsigned)(c2 * 2)], v5 = hp[(unsigned)(c2 * 2 + 1)];
        f16x8 v6 = hp[(unsigned)(c3 * 2)], v7 = hp[(unsigned)(c3 * 2 + 1)];
        #pragma unroll
        for (int k = 0; k < 8; k++) {
            a0[k] += (float)v0[k] + (float)v2[k];
            a0[k + 8] += (float)v1[k] + (float)v3[k];
            a1[k] += (float)v4[k] + (float)v6[k];
            a1[k + 8] += (float)v5[k] + (float)v7[k];
        }
    }
    for (; j < e; ++j) {
        int c = col[j];
        f16x8 v0 = hp[(unsigned)(c * 2)], v1 = hp[(unsigned)(c * 2 + 1)];
        #pragma unroll
        for (int k = 0; k < 8; k++) { a0[k] += (float)v0[k]; a0[k + 8] += (float)v1[k]; }
    }
    float di = dinv[node];
    f16x8 s0 = hp[(unsigned)(node * 2)];
    f16x8 s1 = hp[(unsigned)(node * 2 + 1)];
    const float* bp = bias + s * 16;
    float o[16];
    #pragma unroll
    for (int k = 0; k < 8; k++) {
        o[k] = fmaf(a0[k] + a1[k] + (float)s0[k], di, bp[k]);
        o[k + 8] = fmaf(a0[k + 8] + a1[k + 8] + (float)s1[k], di, bp[k + 8]);
    }
    if (RELU) {
        #pragma unroll
        for (int k = 0; k < 16; k++) o[k] = fmaxf(o[k], 0.f);
    }
    if (OUT16) {
        f16x8 w0, w1;
        #pragma unroll
        for (int k = 0; k < 8; k++) { w0[k] = (f16)o[k]; w1[k] = (f16)o[k + 8]; }
        f16x8* op = (f16x8*)outv;
        op[((size_t)s * NN + node) * 2] = w0;
        op[((size_t)s * NN + node) * 2 + 1] = w1;
    } else {
        float* op = (float*)outv + (size_t)node * (NSLICE * 16) + s * 16;
        #pragma unroll
        for (int k = 0; k < 4; k++)
            *(float4*)(op + k * 4) = make_float4(o[k * 4], o[k * 4 + 1], o[k * 4 + 2], o[k * 4 + 3]);
    }
}

extern "C" void kernel_launch(void* const* d_in, const int* in_sizes, int n_in,
                              void* d_out, int out_size, void* d_ws, size_t ws_size,
                              hipStream_t stream) {
    const float* x  = (const float*)d_in[0];
    const void*  ei = d_in[1];
    const float* W1 = (const float*)d_in[2];
    const float* b1 = (const float*)d_in[3];
    const float* W2 = (const float*)d_in[4];
    const float* b2 = (const float*)d_in[5];
    float* out = (float*)d_out;

    char* wsp = (char*)d_ws;
    size_t off = 0;
    auto alloc = [&](size_t bytes) {
        void* p = wsp + off;
        off += (bytes + 255) & ~(size_t)255;
        return p;
    };
    f16*      h1     = (f16*)alloc((size_t)NN * 128 * 2);  // slice-major [8][NN][16]
    f16*      a1     = (f16*)alloc((size_t)NN * 128 * 2);  // slice-major [8][NN][16]
    f16*      h2     = (f16*)alloc((size_t)NN * 64 * 2);   // slice-major [4][NN][16]
    unsigned* col32  = (unsigned*)alloc((size_t)NB * BCAP * 4);  // 7.2MB
    int*      col    = (int*)alloc((size_t)NB * BCAP * 4);       // 7.2MB (bucket slots)
    int2*     rsp    = (int2*)alloc((size_t)NN * 8);             // (start, deg)
    float*    dinv   = (float*)alloc((size_t)NN * 4);
    int*      cursor = (int*)alloc((size_t)NB * 4);
    f16*      W1h    = (f16*)alloc(128 * 128 * 2);
    f16*      W1l    = (f16*)alloc(128 * 128 * 2);
    f16*      W2h    = (f16*)alloc(64 * 128 * 2);
    f16*      W2l    = (f16*)alloc(64 * 128 * 2);
    (void)ws_size; (void)in_sizes; (void)n_in; (void)out_size;

    prep_split<<<96, 256, 0, stream>>>(W1, W2, W1h, W1l, W2h, W2l);
    init_buckets<<<2, 256, 0, stream>>>(cursor);
    partition_kernel<<<PBLK, 256, 0, stream>>>(ei, cursor, col32);
    bucket_fill_kernel<<<NB, 256, 0, stream>>>(col32, cursor, rsp, dinv, col);

    gemm_mfma<128, 1><<<(NN + 63) / 64, 256, 0, stream>>>(x, W1h, W1l, dinv, h1);
    agg_seq<8, true, true><<<NB * 8, 256, 0, stream>>>(h1, rsp, col, dinv, b1, a1);
    gemm_mfma<64, 0><<<(NN + 63) / 64, 256, 0, stream>>>(a1, W2h, W2l, dinv, h2);
    agg_seq<4, false, false><<<NB * 4, 256, 0, stream>>>(h2, rsp, col, dinv, b2, out);
}